// Round 8
// baseline (113.460 us; speedup 1.0000x reference)
//
#include <hip/hip_runtime.h>
#include <stdint.h>

#define HASH_MASK 524287u        // HASHMAP_SIZE - 1 (2^19)
#define PRIME1 2654435761u
#define PRIME2 805459861u
#define RES 128.0f

typedef float f4 __attribute__((ext_vector_type(4)));
typedef float f2 __attribute__((ext_vector_type(2)));

#define WAITV_(N) asm volatile("s_waitcnt vmcnt(" #N ")" ::: "memory")
#define WAITV(N) do { WAITV_(N); __builtin_amdgcn_sched_barrier(0); } while (0)

// 2 points per thread. Parity-split gathers:
//   A = dwordx4 at ((h0&~1)<<3): the aligned 16B block holding the x-low
//       entry (and, when ix is even, ALSO the x-high entry h0^1).
//   B = dwordx2 at the x-high entry, issued ONLY for lanes with ix odd
//       (divergent exec mask -> ~half the lanes' addresses skipped).
// Gather addr count/point: 4 (A, all lanes) + 4*~0.5 (B, odd lanes) ~= 6.
__global__ __launch_bounds__(256) void hashgrid_fwd(
    const float* __restrict__ x,    // N*3 fp32
    const float* __restrict__ emb,  // H*2 fp32
    float* __restrict__ out,        // N*2 fp32
    int nthreads)                   // N/2
{
    int t = blockIdx.x * blockDim.x + threadIdx.x;
    if (t >= nthreads) return;

    // 2 points = 6 floats = 3 coalesced 8B nt loads (lane stride 24B, dense)
    const f2* xv = reinterpret_cast<const f2*>(x) + (size_t)t * 3;
    f2 q0 = __builtin_nontemporal_load(xv);
    f2 q1 = __builtin_nontemporal_load(xv + 1);
    f2 q2 = __builtin_nontemporal_load(xv + 2);

    const float P[2][3] = {{q0.x, q0.y, q1.x}, {q1.y, q2.x, q2.y}};

    uint32_t h0v[8];     // x-low corner entry index [4*p + m]
    uint32_t offB[8];    // byte offset of x-high corner entry
    float fr[6];
    bool oddp[2];

    #pragma unroll
    for (int p = 0; p < 2; ++p) {
        float fx = P[p][0] * RES, fy = P[p][1] * RES, fz = P[p][2] * RES;
        float flx = floorf(fx), fly = floorf(fy), flz = floorf(fz);
        int ix = (int)flx, iy = (int)fly, iz = (int)flz;
        fr[3*p+0] = fx - flx; fr[3*p+1] = fy - fly; fr[3*p+2] = fz - flz;
        oddp[p] = (ix & 1) != 0;

        uint32_t hx_lo = (uint32_t)ix;           // x prime = 1
        uint32_t hx_hi = hx_lo + 1u;
        uint32_t h1a = (uint32_t)iy * PRIME1, h1b = h1a + PRIME1;
        uint32_t h2a = (uint32_t)iz * PRIME2, h2b = h2a + PRIME2;

        #pragma unroll
        for (int m = 0; m < 4; ++m) {            // m: bit0=y-hi, bit1=z-hi
            uint32_t hyz = ((m & 1) ? h1b : h1a) ^ ((m & 2) ? h2b : h2a);
            h0v[4*p+m]  = (hx_lo ^ hyz) & HASH_MASK;
            offB[4*p+m] = ((hx_hi ^ hyz) & HASH_MASK) << 3;
        }
    }

    // ---- A loads: all lanes, 8 instrs ----
    f4 vA[8];
    #pragma unroll
    for (int i = 0; i < 8; ++i) {
        uint32_t offA = (h0v[i] & ~1u) << 3;     // aligned 16B block
        asm volatile("global_load_dwordx4 %0, %1, %2"
                     : "=v"(vA[i]) : "v"(offA), "s"(emb));
    }

    // ---- B loads: exec-masked to odd-ix lanes only ----
    f2 vB[8];
    if (oddp[0]) {
        #pragma unroll
        for (int i = 0; i < 4; ++i)
            asm volatile("global_load_dwordx2 %0, %1, %2"
                         : "=v"(vB[i]) : "v"(offB[i]), "s"(emb));
    }
    if (oddp[1]) {
        #pragma unroll
        for (int i = 4; i < 8; ++i)
            asm volatile("global_load_dwordx2 %0, %1, %2"
                         : "=v"(vB[i]) : "v"(offB[i]), "s"(emb));
    }

    // ---- weights while gathers are in flight (VALU under vmcnt shadow) ----
    float wyzv[8], wxav[2], wxbv[2];
    #pragma unroll
    for (int p = 0; p < 2; ++p) {
        wxav[p] = 1.f - fr[3*p+0]; wxbv[p] = fr[3*p+0];
        float wya = 1.f - fr[3*p+1], wyb = fr[3*p+1];
        float wza = 1.f - fr[3*p+2], wzb = fr[3*p+2];
        #pragma unroll
        for (int m = 0; m < 4; ++m)
            wyzv[4*p+m] = (((m & 1) ? wyb : wya)) * ((m & 2) ? wzb : wza);
    }

    // branch-dependent vmcnt -> single full wait before any consumption
    WAITV(0);

    float s[4];
    #pragma unroll
    for (int p = 0; p < 2; ++p) {
        float a0 = 0.f, a1 = 0.f;
        #pragma unroll
        for (int m = 0; m < 4; ++m) {
            f4 A = vA[4*p+m];
            f2 B = vB[4*p+m];
            bool hiHalf = (h0v[4*p+m] & 1u) != 0;
            float lo0 = hiHalf ? A.z : A.x;      // x-low entry
            float lo1 = hiHalf ? A.w : A.y;
            float ho0 = hiHalf ? A.x : A.z;      // other half (= x-high if even)
            float ho1 = hiHalf ? A.y : A.w;
            float hi0 = oddp[p] ? B.x : ho0;
            float hi1 = oddp[p] ? B.y : ho1;
            float g0 = fmaf(lo0, wxav[p], hi0 * wxbv[p]);
            float g1 = fmaf(lo1, wxav[p], hi1 * wxbv[p]);
            a0 = fmaf(wyzv[4*p+m], g0, a0);
            a1 = fmaf(wyzv[4*p+m], g1, a1);
        }
        s[2*p+0] = a0; s[2*p+1] = a1;
    }

    // 2 points * float2 = 1 coalesced 16B nt store
    f4 o = {s[0], s[1], s[2], s[3]};
    __builtin_nontemporal_store(o, reinterpret_cast<f4*>(out) + t);
}

// safety net for npts % 2 != 0 (not hit at N=4M)
__global__ void hashgrid_tail(const float* __restrict__ x,
                              const float* __restrict__ emb,
                              float* __restrict__ out,
                              int start, int npts)
{
    int p = start + blockIdx.x * blockDim.x + threadIdx.x;
    if (p >= npts) return;
    float fx = x[3*p] * RES, fy = x[3*p+1] * RES, fz = x[3*p+2] * RES;
    float flx = floorf(fx), fly = floorf(fy), flz = floorf(fz);
    int ix = (int)flx, iy = (int)fly, iz = (int)flz;
    float tx = fx - flx, ty = fy - fly, tz = fz - flz;
    uint32_t h0a = (uint32_t)ix,          h0b = h0a + 1u;
    uint32_t h1a = (uint32_t)iy * PRIME1, h1b = h1a + PRIME1;
    uint32_t h2a = (uint32_t)iz * PRIME2, h2b = h2a + PRIME2;
    const f2* ev = reinterpret_cast<const f2*>(emb);
    float s0 = 0.f, s1 = 0.f;
    #pragma unroll
    for (int n = 0; n < 8; ++n) {
        uint32_t h = ((n & 1) ? h0b : h0a)
                   ^ ((n & 2) ? h1b : h1a)
                   ^ ((n & 4) ? h2b : h2a);
        float w = (((n & 1) ? tx : 1.f - tx) * ((n & 2) ? ty : 1.f - ty))
                  * ((n & 4) ? tz : 1.f - tz);
        f2 e = ev[h & HASH_MASK];
        s0 = fmaf(e.x, w, s0);
        s1 = fmaf(e.y, w, s1);
    }
    out[2*p]   = s0;
    out[2*p+1] = s1;
}

extern "C" void kernel_launch(void* const* d_in, const int* in_sizes, int n_in,
                              void* d_out, int out_size, void* d_ws, size_t ws_size,
                              hipStream_t stream) {
    const float* x   = (const float*)d_in[0];   // N*3
    const float* emb = (const float*)d_in[1];   // H*2
    float* out = (float*)d_out;                 // N*2

    int npts = in_sizes[0] / 3;                 // 4,000,000
    int nthreads = npts / 2;                    // 2,000,000
    int block = 256;
    int grid = (nthreads + block - 1) / block;  // 7813

    hashgrid_fwd<<<grid, block, 0, stream>>>(x, emb, out, nthreads);

    int done = nthreads * 2;
    int rem = npts - done;
    if (rem > 0) {
        int tg = (rem + 255) / 256;
        hashgrid_tail<<<tg, 256, 0, stream>>>(x, emb, out, done, npts);
    }
}

// Round 9
// 97.375 us; speedup vs baseline: 1.1652x; 1.1652x over previous
//
#include <hip/hip_runtime.h>
#include <stdint.h>

#define HASH_MASK 524287u        // HASHMAP_SIZE - 1
#define PRIME1 2654435761u
#define PRIME2 805459861u
#define RES 128.0f

typedef float f4 __attribute__((ext_vector_type(4)));
typedef float f2 __attribute__((ext_vector_type(2)));

// Best-measured structure (R4, 97.4 us): 4 points/thread one-shot burst,
// 32 asm gathers held live (forces real MLP), staged vmcnt consumption.
// Model note: 5 structural variants pin at ~0.65 lane-VMEM-issues/cyc/CU
// (same rate as the HBM-bound float4 copy); with 10 mandatory lane-issues
// per point this is the structural floor (~98 us). Keep this kernel.
__global__ __launch_bounds__(256) void hashgrid_fwd(
    const float* __restrict__ x,    // N*3 fp32
    const float* __restrict__ emb,  // H*2 fp32
    float* __restrict__ out,        // N*2 fp32
    int nthreads)                   // N/4
{
    int t = blockIdx.x * blockDim.x + threadIdx.x;
    if (t >= nthreads) return;

    // 4 points = 12 floats = 3 coalesced float4 loads (nontemporal stream)
    const f4* xv = reinterpret_cast<const f4*>(x) + (size_t)t * 3;
    f4 a = __builtin_nontemporal_load(xv);
    f4 b = __builtin_nontemporal_load(xv + 1);
    f4 c = __builtin_nontemporal_load(xv + 2);

    const float px[12] = {a.x, a.y, a.z, a.w,
                          b.x, b.y, b.z, b.w,
                          c.x, c.y, c.z, c.w};

    // ---- Phase 1: all 32 byte offsets + fractional parts ----
    uint32_t off[32];
    float txf[4], tyf[4], tzf[4];
    #pragma unroll
    for (int p = 0; p < 4; ++p) {
        float fx = px[p * 3 + 0] * RES;
        float fy = px[p * 3 + 1] * RES;
        float fz = px[p * 3 + 2] * RES;
        float flx = floorf(fx), fly = floorf(fy), flz = floorf(fz);
        int ix = (int)flx, iy = (int)fly, iz = (int)flz;
        txf[p] = fx - flx;
        tyf[p] = fy - fly;
        tzf[p] = fz - flz;

        uint32_t h0a = (uint32_t)ix;          // * 1
        uint32_t h0b = h0a + 1u;
        uint32_t h1a = (uint32_t)iy * PRIME1;
        uint32_t h1b = h1a + PRIME1;
        uint32_t h2a = (uint32_t)iz * PRIME2;
        uint32_t h2b = h2a + PRIME2;

        #pragma unroll
        for (int n = 0; n < 8; ++n) {
            // bit d of n clear -> lower index in dim d (matches BIN_MASK)
            uint32_t h = ((n & 1) ? h0b : h0a)
                       ^ ((n & 2) ? h1b : h1a)
                       ^ ((n & 4) ? h2b : h2a);
            off[p * 8 + n] = (h & HASH_MASK) << 3;   // float2 = 8 bytes
        }
    }

    // ---- Phase 2: 32 gathers via inline asm (saddr form: 32b voffset +
    // SGPR base). asm volatile keeps issue order; 64 "=v" result VGPRs are
    // forced live -> 32 loads genuinely in flight per wave. ----
    f2 e[32];
    #pragma unroll
    for (int i = 0; i < 32; ++i) {
        asm volatile("global_load_dwordx2 %0, %1, %2"
                     : "=v"(e[i])
                     : "v"(off[i]), "s"(emb));
    }

    // ---- Phase 3: weights (VALU under the vmcnt shadow) ----
    float wgt[32];
    #pragma unroll
    for (int p = 0; p < 4; ++p) {
        float wxa = 1.0f - txf[p], wxb = txf[p];
        float wya = 1.0f - tyf[p], wyb = tyf[p];
        float wza = 1.0f - tzf[p], wzb = tzf[p];
        #pragma unroll
        for (int n = 0; n < 8; ++n) {
            wgt[p * 8 + n] = (((n & 1) ? wxb : wxa) * ((n & 2) ? wyb : wya))
                             * ((n & 4) ? wzb : wza);
        }
    }

    // ---- Phase 4: staged consumption. vmcnt returns are in issue order:
    // vmcnt(24) -> point 0's 8 loads done, etc. sched_barrier(0) after each
    // wait pins consumers below it (asm waitcnt alone is hoistable).
    float s[8];

    asm volatile("s_waitcnt vmcnt(24)" ::: "memory");
    __builtin_amdgcn_sched_barrier(0);
    {
        float s0 = 0.0f, s1 = 0.0f;
        #pragma unroll
        for (int n = 0; n < 8; ++n) {
            s0 = fmaf(e[n].x, wgt[n], s0);
            s1 = fmaf(e[n].y, wgt[n], s1);
        }
        s[0] = s0; s[1] = s1;
    }

    asm volatile("s_waitcnt vmcnt(16)" ::: "memory");
    __builtin_amdgcn_sched_barrier(0);
    {
        float s0 = 0.0f, s1 = 0.0f;
        #pragma unroll
        for (int n = 0; n < 8; ++n) {
            s0 = fmaf(e[8 + n].x, wgt[8 + n], s0);
            s1 = fmaf(e[8 + n].y, wgt[8 + n], s1);
        }
        s[2] = s0; s[3] = s1;
    }

    asm volatile("s_waitcnt vmcnt(8)" ::: "memory");
    __builtin_amdgcn_sched_barrier(0);
    {
        float s0 = 0.0f, s1 = 0.0f;
        #pragma unroll
        for (int n = 0; n < 8; ++n) {
            s0 = fmaf(e[16 + n].x, wgt[16 + n], s0);
            s1 = fmaf(e[16 + n].y, wgt[16 + n], s1);
        }
        s[4] = s0; s[5] = s1;
    }

    asm volatile("s_waitcnt vmcnt(0)" ::: "memory");
    __builtin_amdgcn_sched_barrier(0);
    {
        float s0 = 0.0f, s1 = 0.0f;
        #pragma unroll
        for (int n = 0; n < 8; ++n) {
            s0 = fmaf(e[24 + n].x, wgt[24 + n], s0);
            s1 = fmaf(e[24 + n].y, wgt[24 + n], s1);
        }
        s[6] = s0; s[7] = s1;
    }

    // 4 points * float2 = 2 coalesced float4 stores (nontemporal)
    f4* ov = reinterpret_cast<f4*>(out) + (size_t)t * 2;
    f4 o0 = {s[0], s[1], s[2], s[3]};
    f4 o1 = {s[4], s[5], s[6], s[7]};
    __builtin_nontemporal_store(o0, ov);
    __builtin_nontemporal_store(o1, ov + 1);
}

extern "C" void kernel_launch(void* const* d_in, const int* in_sizes, int n_in,
                              void* d_out, int out_size, void* d_ws, size_t ws_size,
                              hipStream_t stream) {
    const float* x   = (const float*)d_in[0];   // N*3
    const float* emb = (const float*)d_in[1];   // H*2
    float* out = (float*)d_out;                 // N*2

    int npts = in_sizes[0] / 3;                 // 4,000,000
    int nthreads = npts / 4;                    // 1,000,000
    int block = 256;
    int grid = (nthreads + block - 1) / block;  // 3907

    hashgrid_fwd<<<grid, block, 0, stream>>>(x, emb, out, nthreads);
}